// Round 1
// baseline (9344.596 us; speedup 1.0000x reference)
//
#include <hip/hip_runtime.h>
#include <math.h>

#define BATCH 1024

// ---------------- LeNet conv1 (3->6, 5x5 VALID) + ReLU + 2x2 maxpool ----------------
__global__ __launch_bounds__(256) void lenet_conv1(const float* __restrict__ x,
    const float* __restrict__ w, const float* __restrict__ bias, float* __restrict__ p1)
{
    __shared__ float img[3 * 1024];
    __shared__ float wl[450];
    __shared__ float bl[6];
    int b = blockIdx.x, t = threadIdx.x;
    for (int i = t; i < 3072; i += 256) img[i] = x[(size_t)b * 3072 + i];
    for (int i = t; i < 450; i += 256) wl[i] = w[i];
    if (t < 6) bl[t] = bias[t];
    __syncthreads();
    for (int idx = t; idx < 1176; idx += 256) {
        int o = idx / 196, r = idx - o * 196, py = r / 14, px = r - py * 14;
        int y0 = 2 * py, x0 = 2 * px;
        float s00, s01, s10, s11;
        s00 = s01 = s10 = s11 = bl[o];
        for (int c = 0; c < 3; c++) {
            float pv[6][6];
            #pragma unroll
            for (int i2 = 0; i2 < 6; i2++)
                #pragma unroll
                for (int j2 = 0; j2 < 6; j2++)
                    pv[i2][j2] = img[c * 1024 + (y0 + i2) * 32 + x0 + j2];
            const float* wc = &wl[o * 75 + c * 25];
            #pragma unroll
            for (int ky = 0; ky < 5; ky++)
                #pragma unroll
                for (int kx = 0; kx < 5; kx++) {
                    float wv = wc[ky * 5 + kx];
                    s00 += pv[ky][kx] * wv;
                    s01 += pv[ky][kx + 1] * wv;
                    s10 += pv[ky + 1][kx] * wv;
                    s11 += pv[ky + 1][kx + 1] * wv;
                }
        }
        float m = fmaxf(fmaxf(s00, s01), fmaxf(s10, s11));
        p1[(size_t)b * 1176 + idx] = fmaxf(m, 0.f);
    }
}

// ---------------- LeNet conv2 (6->16, 5x5 VALID) + ReLU + 2x2 maxpool ----------------
__global__ __launch_bounds__(256) void lenet_conv2(const float* __restrict__ p1,
    const float* __restrict__ w, const float* __restrict__ bias, float* __restrict__ p2)
{
    __shared__ float img[1176];   // [6][14][14]
    __shared__ float wl[2400];    // [16][6][5][5]
    __shared__ float bl[16];
    int b = blockIdx.x, t = threadIdx.x;
    for (int i = t; i < 1176; i += 256) img[i] = p1[(size_t)b * 1176 + i];
    for (int i = t; i < 2400; i += 256) wl[i] = w[i];
    if (t < 16) bl[t] = bias[t];
    __syncthreads();
    for (int idx = t; idx < 400; idx += 256) {
        int o = idx / 25, r = idx - o * 25, py = r / 5, px = r - py * 5;
        int y0 = 2 * py, x0 = 2 * px;
        float s00, s01, s10, s11;
        s00 = s01 = s10 = s11 = bl[o];
        for (int c = 0; c < 6; c++) {
            float pv[6][6];
            #pragma unroll
            for (int i2 = 0; i2 < 6; i2++)
                #pragma unroll
                for (int j2 = 0; j2 < 6; j2++)
                    pv[i2][j2] = img[c * 196 + (y0 + i2) * 14 + x0 + j2];
            const float* wc = &wl[o * 150 + c * 25];
            #pragma unroll
            for (int ky = 0; ky < 5; ky++)
                #pragma unroll
                for (int kx = 0; kx < 5; kx++) {
                    float wv = wc[ky * 5 + kx];
                    s00 += pv[ky][kx] * wv;
                    s01 += pv[ky][kx + 1] * wv;
                    s10 += pv[ky + 1][kx] * wv;
                    s11 += pv[ky + 1][kx + 1] * wv;
                }
        }
        float m = fmaxf(fmaxf(s00, s01), fmaxf(s10, s11));
        p2[(size_t)b * 400 + idx] = fmaxf(m, 0.f);
    }
}

// ---------------- LeNet FC head + argmax + conf-matrix + low-conf flag ----------------
__global__ __launch_bounds__(128) void lenet_fc(const float* __restrict__ p2,
    const float* __restrict__ w1, const float* __restrict__ b1,
    const float* __restrict__ w2, const float* __restrict__ b2,
    const float* __restrict__ w3, const float* __restrict__ b3,
    const int* __restrict__ labels, const float* __restrict__ thr,
    float* __restrict__ out, float* __restrict__ conf, int* __restrict__ flags)
{
    __shared__ float xin[400];
    __shared__ float h1[120];
    __shared__ float h2[84];
    __shared__ float lg[10];
    int b = blockIdx.x, t = threadIdx.x;
    for (int i = t; i < 400; i += 128) xin[i] = p2[(size_t)b * 400 + i];
    __syncthreads();
    if (t < 120) {
        float s = b1[t];
        for (int k = 0; k < 400; k++) s += xin[k] * w1[k * 120 + t];
        h1[t] = fmaxf(s, 0.f);
    }
    __syncthreads();
    if (t < 84) {
        float s = b2[t];
        for (int k = 0; k < 120; k++) s += h1[k] * w2[k * 84 + t];
        h2[t] = fmaxf(s, 0.f);
    }
    __syncthreads();
    if (t < 10) {
        float s = b3[t];
        for (int k = 0; k < 84; k++) s += h2[k] * w3[k * 10 + t];
        lg[t] = s;
        out[(size_t)b * 10 + t] = s;
    }
    __syncthreads();
    if (t == 0) {
        int pred = 0;
        float m = lg[0];
        #pragma unroll
        for (int j = 1; j < 10; j++) if (lg[j] > m) { m = lg[j]; pred = j; }
        float se = 0.f, m2 = -1e30f;
        #pragma unroll
        for (int j = 0; j < 10; j++) {
            se += expf(lg[j] - m);
            if (j != pred) m2 = fmaxf(m2, lg[j]);
        }
        float gap = (1.f - expf(m2 - m)) / se;   // p_top1 - p_top2
        flags[b] = (gap <= thr[0]) ? 1 : 0;
        atomicAdd(&conf[labels[b] * 10 + pred], 1.f);
    }
}

// ---------------- ResNet 3x3 SAME conv, fused bias(+skip)+ReLU ----------------
// block = 128 threads: one image x 8 output channels, full 32x32.
// Each thread: 8 consecutive px in a row, for 8 c_out (64 accumulators).
template<int CIN, bool ADD>
__global__ __launch_bounds__(128) void conv3x3k(const float* __restrict__ in,
    const float* __restrict__ w, const float* __restrict__ bias,
    const float* __restrict__ skip, float* __restrict__ out)
{
    __shared__ float sl[34 * 35];   // padded input slice, row stride 35
    int blk = blockIdx.x;
    int b = blk >> 3;
    int co0 = (blk & 7) * 8;
    int t = threadIdx.x;
    int y = t >> 2, x0 = (t & 3) * 8;

    float acc[8][8];
    #pragma unroll
    for (int i = 0; i < 8; i++)
        #pragma unroll
        for (int j = 0; j < 8; j++) acc[i][j] = 0.f;

    for (int ci = 0; ci < CIN; ci++) {
        __syncthreads();
        for (int i = t; i < 1156; i += 128) {
            int r = i / 34, c = i - r * 34;
            int yy = r - 1, xx = c - 1;
            float v = 0.f;
            if (yy >= 0 && yy < 32 && xx >= 0 && xx < 32)
                v = in[((size_t)b * CIN + ci) * 1024 + yy * 32 + xx];
            sl[r * 35 + c] = v;
        }
        __syncthreads();
        float iv[3][10];
        #pragma unroll
        for (int dy = 0; dy < 3; dy++)
            #pragma unroll
            for (int dx = 0; dx < 10; dx++)
                iv[dy][dx] = sl[(y + dy) * 35 + x0 + dx];
        #pragma unroll
        for (int co = 0; co < 8; co++) {
            const float* wq = w + ((size_t)(co0 + co) * CIN + ci) * 9;  // block-uniform -> s_load
            float w0 = wq[0], w1 = wq[1], w2 = wq[2], w3 = wq[3], w4 = wq[4],
                  w5 = wq[5], w6 = wq[6], w7 = wq[7], w8 = wq[8];
            #pragma unroll
            for (int p = 0; p < 8; p++) {
                acc[co][p] += w0 * iv[0][p] + w1 * iv[0][p + 1] + w2 * iv[0][p + 2]
                            + w3 * iv[1][p] + w4 * iv[1][p + 1] + w5 * iv[1][p + 2]
                            + w6 * iv[2][p] + w7 * iv[2][p + 1] + w8 * iv[2][p + 2];
            }
        }
    }

    #pragma unroll
    for (int co = 0; co < 8; co++) {
        float bv = bias[co0 + co];
        size_t oidx = ((size_t)b * 64 + co0 + co) * 1024 + (size_t)y * 32 + x0;
        #pragma unroll
        for (int p0 = 0; p0 < 8; p0 += 4) {
            float4 r;
            r.x = acc[co][p0 + 0] + bv;
            r.y = acc[co][p0 + 1] + bv;
            r.z = acc[co][p0 + 2] + bv;
            r.w = acc[co][p0 + 3] + bv;
            if (ADD) {
                const float4 s4 = *reinterpret_cast<const float4*>(&skip[oidx + p0]);
                r.x += s4.x; r.y += s4.y; r.z += s4.z; r.w += s4.w;
            }
            r.x = fmaxf(r.x, 0.f); r.y = fmaxf(r.y, 0.f);
            r.z = fmaxf(r.z, 0.f); r.w = fmaxf(r.w, 0.f);
            *reinterpret_cast<float4*>(&out[oidx + p0]) = r;
        }
    }
}

// ---------------- ResNet head: global avg pool + FC, masked merge ----------------
__global__ __launch_bounds__(256) void res_head(const float* __restrict__ h,
    const float* __restrict__ rfc, const float* __restrict__ rfb,
    const int* __restrict__ flags, float* __restrict__ out)
{
    __shared__ float mean[64];
    int b = blockIdx.x, t = threadIdx.x;
    int wv = t >> 6, l = t & 63;
    for (int i = 0; i < 16; i++) {
        int c = wv * 16 + i;
        const float* p = h + ((size_t)b * 64 + c) * 1024;
        float s = 0.f;
        #pragma unroll
        for (int j = 0; j < 16; j++) s += p[l + 64 * j];
        #pragma unroll
        for (int off = 32; off > 0; off >>= 1) s += __shfl_xor(s, off, 64);
        if (l == 0) mean[c] = s * (1.f / 1024.f);
    }
    __syncthreads();
    if (t < 10 && flags[b]) {
        float s = rfb[t];
        for (int c = 0; c < 64; c++) s += mean[c] * rfc[c * 10 + t];
        out[(size_t)b * 10 + t] = s;
    }
}

extern "C" void kernel_launch(void* const* d_in, const int* in_sizes, int n_in,
                              void* d_out, int out_size, void* d_ws, size_t ws_size,
                              hipStream_t stream)
{
    const float* x    = (const float*)d_in[0];
    const float* thr  = (const float*)d_in[1];
    const int*   labels = (const int*)d_in[2];
    const float* lw1 = (const float*)d_in[3];  const float* lb1 = (const float*)d_in[4];
    const float* lw2 = (const float*)d_in[5];  const float* lb2 = (const float*)d_in[6];
    const float* lfc1 = (const float*)d_in[7]; const float* lfb1 = (const float*)d_in[8];
    const float* lfc2 = (const float*)d_in[9]; const float* lfb2 = (const float*)d_in[10];
    const float* lfc3 = (const float*)d_in[11];const float* lfb3 = (const float*)d_in[12];
    const float* rw0 = (const float*)d_in[13]; const float* rb0 = (const float*)d_in[14];
    const float* rw1a = (const float*)d_in[15];const float* rb1a = (const float*)d_in[16];
    const float* rw1b = (const float*)d_in[17];const float* rb1b = (const float*)d_in[18];
    const float* rw2a = (const float*)d_in[19];const float* rb2a = (const float*)d_in[20];
    const float* rw2b = (const float*)d_in[21];const float* rb2b = (const float*)d_in[22];
    const float* rfc = (const float*)d_in[23]; const float* rfb = (const float*)d_in[24];

    float* out  = (float*)d_out;
    float* conf = out + (size_t)BATCH * 10;   // 10240

    // Workspace: resnet needs two [chunkB,64,32,32] fp32 buffers + flag array.
    // Pick the largest chunk size that fits ws_size (deterministic per session).
    int nc = 1;
    while (nc < 16 &&
           (2ull * (size_t)(BATCH / nc) * 65536ull + 1024ull) * 4ull > ws_size)
        nc <<= 1;
    int cb = BATCH / nc;

    float* A  = (float*)d_ws;
    float* Bb = A + (size_t)cb * 65536;
    int* flags = (int*)(Bb + (size_t)cb * 65536);

    // LeNet temporaries alias A (dead before resnet conv0 writes A).
    float* p1 = A;               // [B,6,14,14] = 1,204,224 floats
    float* p2 = A + 1204224;     // [B,400]     =   409,600 floats

    hipMemsetAsync(conf, 0, 100 * sizeof(float), stream);

    lenet_conv1<<<BATCH, 256, 0, stream>>>(x, lw1, lb1, p1);
    lenet_conv2<<<BATCH, 256, 0, stream>>>(p1, lw2, lb2, p2);
    lenet_fc<<<BATCH, 128, 0, stream>>>(p2, lfc1, lfb1, lfc2, lfb2, lfc3, lfb3,
                                        labels, thr, out, conf, flags);

    for (int c0 = 0; c0 < BATCH; c0 += cb) {
        const float* xc = x + (size_t)c0 * 3072;
        conv3x3k<3,  false><<<cb * 8, 128, 0, stream>>>(xc, rw0, rb0, nullptr, A);
        conv3x3k<64, false><<<cb * 8, 128, 0, stream>>>(A,  rw1a, rb1a, nullptr, Bb);
        conv3x3k<64, true ><<<cb * 8, 128, 0, stream>>>(Bb, rw1b, rb1b, A, A);
        conv3x3k<64, false><<<cb * 8, 128, 0, stream>>>(A,  rw2a, rb2a, nullptr, Bb);
        conv3x3k<64, true ><<<cb * 8, 128, 0, stream>>>(Bb, rw2b, rb2b, A, A);
        res_head<<<cb, 256, 0, stream>>>(A, rfc, rfb, flags + c0, out + (size_t)c0 * 10);
    }
}

// Round 2
// 4368.511 us; speedup vs baseline: 2.1391x; 2.1391x over previous
//
#include <hip/hip_runtime.h>
#include <math.h>

#define BATCH 1024

// ---------------- LeNet conv1 (3->6, 5x5 VALID) + ReLU + 2x2 maxpool ----------------
__global__ __launch_bounds__(256) void lenet_conv1(const float* __restrict__ x,
    const float* __restrict__ w, const float* __restrict__ bias, float* __restrict__ p1)
{
    __shared__ float img[3 * 1024];
    __shared__ float wl[450];
    __shared__ float bl[6];
    int b = blockIdx.x, t = threadIdx.x;
    for (int i = t; i < 3072; i += 256) img[i] = x[(size_t)b * 3072 + i];
    for (int i = t; i < 450; i += 256) wl[i] = w[i];
    if (t < 6) bl[t] = bias[t];
    __syncthreads();
    for (int idx = t; idx < 1176; idx += 256) {
        int o = idx / 196, r = idx - o * 196, py = r / 14, px = r - py * 14;
        int y0 = 2 * py, x0 = 2 * px;
        float s00, s01, s10, s11;
        s00 = s01 = s10 = s11 = bl[o];
        for (int c = 0; c < 3; c++) {
            float pv[6][6];
            #pragma unroll
            for (int i2 = 0; i2 < 6; i2++)
                #pragma unroll
                for (int j2 = 0; j2 < 6; j2++)
                    pv[i2][j2] = img[c * 1024 + (y0 + i2) * 32 + x0 + j2];
            const float* wc = &wl[o * 75 + c * 25];
            #pragma unroll
            for (int ky = 0; ky < 5; ky++)
                #pragma unroll
                for (int kx = 0; kx < 5; kx++) {
                    float wv = wc[ky * 5 + kx];
                    s00 += pv[ky][kx] * wv;
                    s01 += pv[ky][kx + 1] * wv;
                    s10 += pv[ky + 1][kx] * wv;
                    s11 += pv[ky + 1][kx + 1] * wv;
                }
        }
        float m = fmaxf(fmaxf(s00, s01), fmaxf(s10, s11));
        p1[(size_t)b * 1176 + idx] = fmaxf(m, 0.f);
    }
}

// ---------------- LeNet conv2 (6->16, 5x5 VALID) + ReLU + 2x2 maxpool ----------------
__global__ __launch_bounds__(256) void lenet_conv2(const float* __restrict__ p1,
    const float* __restrict__ w, const float* __restrict__ bias, float* __restrict__ p2)
{
    __shared__ float img[1176];   // [6][14][14]
    __shared__ float wl[2400];    // [16][6][5][5]
    __shared__ float bl[16];
    int b = blockIdx.x, t = threadIdx.x;
    for (int i = t; i < 1176; i += 256) img[i] = p1[(size_t)b * 1176 + i];
    for (int i = t; i < 2400; i += 256) wl[i] = w[i];
    if (t < 16) bl[t] = bias[t];
    __syncthreads();
    for (int idx = t; idx < 400; idx += 256) {
        int o = idx / 25, r = idx - o * 25, py = r / 5, px = r - py * 5;
        int y0 = 2 * py, x0 = 2 * px;
        float s00, s01, s10, s11;
        s00 = s01 = s10 = s11 = bl[o];
        for (int c = 0; c < 6; c++) {
            float pv[6][6];
            #pragma unroll
            for (int i2 = 0; i2 < 6; i2++)
                #pragma unroll
                for (int j2 = 0; j2 < 6; j2++)
                    pv[i2][j2] = img[c * 196 + (y0 + i2) * 14 + x0 + j2];
            const float* wc = &wl[o * 150 + c * 25];
            #pragma unroll
            for (int ky = 0; ky < 5; ky++)
                #pragma unroll
                for (int kx = 0; kx < 5; kx++) {
                    float wv = wc[ky * 5 + kx];
                    s00 += pv[ky][kx] * wv;
                    s01 += pv[ky][kx + 1] * wv;
                    s10 += pv[ky + 1][kx] * wv;
                    s11 += pv[ky + 1][kx + 1] * wv;
                }
        }
        float m = fmaxf(fmaxf(s00, s01), fmaxf(s10, s11));
        p2[(size_t)b * 400 + idx] = fmaxf(m, 0.f);
    }
}

// ---------------- LeNet FC head + argmax + conf-matrix + low-conf flag ----------------
__global__ __launch_bounds__(128) void lenet_fc(const float* __restrict__ p2,
    const float* __restrict__ w1, const float* __restrict__ b1,
    const float* __restrict__ w2, const float* __restrict__ b2,
    const float* __restrict__ w3, const float* __restrict__ b3,
    const int* __restrict__ labels, const float* __restrict__ thr,
    float* __restrict__ out, float* __restrict__ conf, int* __restrict__ flags)
{
    __shared__ float xin[400];
    __shared__ float h1[120];
    __shared__ float h2[84];
    __shared__ float lg[10];
    int b = blockIdx.x, t = threadIdx.x;
    for (int i = t; i < 400; i += 128) xin[i] = p2[(size_t)b * 400 + i];
    __syncthreads();
    if (t < 120) {
        float s = b1[t];
        for (int k = 0; k < 400; k++) s += xin[k] * w1[k * 120 + t];
        h1[t] = fmaxf(s, 0.f);
    }
    __syncthreads();
    if (t < 84) {
        float s = b2[t];
        for (int k = 0; k < 120; k++) s += h1[k] * w2[k * 84 + t];
        h2[t] = fmaxf(s, 0.f);
    }
    __syncthreads();
    if (t < 10) {
        float s = b3[t];
        for (int k = 0; k < 84; k++) s += h2[k] * w3[k * 10 + t];
        lg[t] = s;
        out[(size_t)b * 10 + t] = s;
    }
    __syncthreads();
    if (t == 0) {
        int pred = 0;
        float m = lg[0];
        #pragma unroll
        for (int j = 1; j < 10; j++) if (lg[j] > m) { m = lg[j]; pred = j; }
        float se = 0.f, m2 = -1e30f;
        #pragma unroll
        for (int j = 0; j < 10; j++) {
            se += expf(lg[j] - m);
            if (j != pred) m2 = fmaxf(m2, lg[j]);
        }
        float gap = (1.f - expf(m2 - m)) / se;   // p_top1 - p_top2
        flags[b] = (gap <= thr[0]) ? 1 : 0;
        atomicAdd(&conf[labels[b] * 10 + pred], 1.f);
    }
}

// ---------------- ResNet 3x3 SAME conv, fused bias(+skip)+ReLU ----------------
// block = 256 threads: one image x 16 output channels, full 32x32.
// Thread t: pixels t*4..t*4+3 (row y=t>>3, cols x0..x0+3), 16 c_out -> 64 acc.
// LDS: double-buffered 34x35 padded slice; border is ALWAYS zero (tile = whole
// image) so it is zeroed once and only the 32x32 interior is restaged per c_in.
// One barrier per c_in; next c_in's global float4 load issued before the FMA
// burst so its latency hides under 576 FMAs.
template<int CIN, bool ADD>
__global__ __launch_bounds__(256) void conv3x3v2(const float* __restrict__ in,
    const float* __restrict__ w, const float* __restrict__ bias,
    const float* __restrict__ skip, float* __restrict__ out)
{
    __shared__ float sl[2][34 * 35];
    int blk = blockIdx.x;
    int b = blk >> 2;
    int co0 = (blk & 3) * 16;
    int t = threadIdx.x;
    int y = t >> 3, x0 = (t & 7) * 4;

    // zero borders (rows 0,33; cols 0,33) of both buffers, once
    for (int i = t; i < 35; i += 256) {
        sl[0][i] = 0.f; sl[0][33 * 35 + i] = 0.f;
        sl[1][i] = 0.f; sl[1][33 * 35 + i] = 0.f;
    }
    for (int i = t; i < 34; i += 256) {
        sl[0][i * 35] = 0.f; sl[0][i * 35 + 33] = 0.f;
        sl[1][i * 35] = 0.f; sl[1][i * 35 + 33] = 0.f;
    }

    const float* src = in + (size_t)b * CIN * 1024;
    const int wr = (y + 1) * 35 + 1 + x0;

    // prologue: stage c_in 0 into buffer 0
    float4 pf = *reinterpret_cast<const float4*>(src + t * 4);
    sl[0][wr + 0] = pf.x; sl[0][wr + 1] = pf.y;
    sl[0][wr + 2] = pf.z; sl[0][wr + 3] = pf.w;
    __syncthreads();

    float acc[16][4];
    #pragma unroll
    for (int i = 0; i < 16; i++)
        #pragma unroll
        for (int j = 0; j < 4; j++) acc[i][j] = 0.f;

    const float* wbase = w + (size_t)co0 * CIN * 9;

    int p = 0;
    for (int ci = 0; ci < CIN; ci++) {
        // issue prefetch of next slice early; latency hides under the FMAs
        if (ci + 1 < CIN)
            pf = *reinterpret_cast<const float4*>(src + (size_t)(ci + 1) * 1024 + t * 4);

        float iv[3][6];
        #pragma unroll
        for (int dy = 0; dy < 3; dy++)
            #pragma unroll
            for (int j = 0; j < 6; j++)
                iv[dy][j] = sl[p][(y + dy) * 35 + x0 + j];

        #pragma unroll
        for (int co = 0; co < 16; co++) {
            const float* wq = wbase + ((size_t)co * CIN + ci) * 9;  // block-uniform -> s_load
            float w0 = wq[0], w1 = wq[1], w2 = wq[2], w3 = wq[3], w4 = wq[4],
                  w5 = wq[5], w6 = wq[6], w7 = wq[7], w8 = wq[8];
            #pragma unroll
            for (int px = 0; px < 4; px++) {
                acc[co][px] += w0 * iv[0][px] + w1 * iv[0][px + 1] + w2 * iv[0][px + 2]
                             + w3 * iv[1][px] + w4 * iv[1][px + 1] + w5 * iv[1][px + 2]
                             + w6 * iv[2][px] + w7 * iv[2][px + 1] + w8 * iv[2][px + 2];
            }
        }

        if (ci + 1 < CIN) {
            int q = p ^ 1;
            sl[q][wr + 0] = pf.x; sl[q][wr + 1] = pf.y;
            sl[q][wr + 2] = pf.z; sl[q][wr + 3] = pf.w;
            __syncthreads();   // single barrier per c_in (see hazard note)
            p = q;
        }
    }

    #pragma unroll
    for (int co = 0; co < 16; co++) {
        float bv = bias[co0 + co];
        size_t oidx = ((size_t)b * 64 + co0 + co) * 1024 + (size_t)t * 4;
        float4 r;
        r.x = acc[co][0] + bv; r.y = acc[co][1] + bv;
        r.z = acc[co][2] + bv; r.w = acc[co][3] + bv;
        if (ADD) {
            const float4 s4 = *reinterpret_cast<const float4*>(&skip[oidx]);
            r.x += s4.x; r.y += s4.y; r.z += s4.z; r.w += s4.w;
        }
        r.x = fmaxf(r.x, 0.f); r.y = fmaxf(r.y, 0.f);
        r.z = fmaxf(r.z, 0.f); r.w = fmaxf(r.w, 0.f);
        *reinterpret_cast<float4*>(&out[oidx]) = r;
    }
}

// ---------------- ResNet head: global avg pool + FC, masked merge ----------------
__global__ __launch_bounds__(256) void res_head(const float* __restrict__ h,
    const float* __restrict__ rfc, const float* __restrict__ rfb,
    const int* __restrict__ flags, float* __restrict__ out)
{
    __shared__ float mean[64];
    int b = blockIdx.x, t = threadIdx.x;
    int wv = t >> 6, l = t & 63;
    for (int i = 0; i < 16; i++) {
        int c = wv * 16 + i;
        const float* p = h + ((size_t)b * 64 + c) * 1024;
        float s = 0.f;
        #pragma unroll
        for (int j = 0; j < 16; j++) s += p[l + 64 * j];
        #pragma unroll
        for (int off = 32; off > 0; off >>= 1) s += __shfl_xor(s, off, 64);
        if (l == 0) mean[c] = s * (1.f / 1024.f);
    }
    __syncthreads();
    if (t < 10 && flags[b]) {
        float s = rfb[t];
        for (int c = 0; c < 64; c++) s += mean[c] * rfc[c * 10 + t];
        out[(size_t)b * 10 + t] = s;
    }
}

extern "C" void kernel_launch(void* const* d_in, const int* in_sizes, int n_in,
                              void* d_out, int out_size, void* d_ws, size_t ws_size,
                              hipStream_t stream)
{
    const float* x    = (const float*)d_in[0];
    const float* thr  = (const float*)d_in[1];
    const int*   labels = (const int*)d_in[2];
    const float* lw1 = (const float*)d_in[3];  const float* lb1 = (const float*)d_in[4];
    const float* lw2 = (const float*)d_in[5];  const float* lb2 = (const float*)d_in[6];
    const float* lfc1 = (const float*)d_in[7]; const float* lfb1 = (const float*)d_in[8];
    const float* lfc2 = (const float*)d_in[9]; const float* lfb2 = (const float*)d_in[10];
    const float* lfc3 = (const float*)d_in[11];const float* lfb3 = (const float*)d_in[12];
    const float* rw0 = (const float*)d_in[13]; const float* rb0 = (const float*)d_in[14];
    const float* rw1a = (const float*)d_in[15];const float* rb1a = (const float*)d_in[16];
    const float* rw1b = (const float*)d_in[17];const float* rb1b = (const float*)d_in[18];
    const float* rw2a = (const float*)d_in[19];const float* rb2a = (const float*)d_in[20];
    const float* rw2b = (const float*)d_in[21];const float* rb2b = (const float*)d_in[22];
    const float* rfc = (const float*)d_in[23]; const float* rfb = (const float*)d_in[24];

    float* out  = (float*)d_out;
    float* conf = out + (size_t)BATCH * 10;   // 10240

    // Workspace: two [chunkB,64,32,32] fp32 buffers + flag array; pick largest
    // chunk that fits ws_size (deterministic per session).
    int nc = 1;
    while (nc < 16 &&
           (2ull * (size_t)(BATCH / nc) * 65536ull + 1024ull) * 4ull > ws_size)
        nc <<= 1;
    int cb = BATCH / nc;

    float* A  = (float*)d_ws;
    float* Bb = A + (size_t)cb * 65536;
    int* flags = (int*)(Bb + (size_t)cb * 65536);

    // LeNet temporaries alias A (dead before resnet conv0 writes A).
    float* p1 = A;               // [B,6,14,14] = 1,204,224 floats
    float* p2 = A + 1204224;     // [B,400]     =   409,600 floats

    hipMemsetAsync(conf, 0, 100 * sizeof(float), stream);

    lenet_conv1<<<BATCH, 256, 0, stream>>>(x, lw1, lb1, p1);
    lenet_conv2<<<BATCH, 256, 0, stream>>>(p1, lw2, lb2, p2);
    lenet_fc<<<BATCH, 128, 0, stream>>>(p2, lfc1, lfb1, lfc2, lfb2, lfc3, lfb3,
                                        labels, thr, out, conf, flags);

    for (int c0 = 0; c0 < BATCH; c0 += cb) {
        const float* xc = x + (size_t)c0 * 3072;
        conv3x3v2<3,  false><<<cb * 4, 256, 0, stream>>>(xc, rw0, rb0, nullptr, A);
        conv3x3v2<64, false><<<cb * 4, 256, 0, stream>>>(A,  rw1a, rb1a, nullptr, Bb);
        conv3x3v2<64, true ><<<cb * 4, 256, 0, stream>>>(Bb, rw1b, rb1b, A, A);
        conv3x3v2<64, false><<<cb * 4, 256, 0, stream>>>(A,  rw2a, rb2a, nullptr, Bb);
        conv3x3v2<64, true ><<<cb * 4, 256, 0, stream>>>(Bb, rw2b, rb2b, A, A);
        res_head<<<cb, 256, 0, stream>>>(A, rfc, rfb, flags + c0, out + (size_t)c0 * 10);
    }
}

// Round 3
// 1516.582 us; speedup vs baseline: 6.1616x; 2.8805x over previous
//
#include <hip/hip_runtime.h>
#include <hip/hip_bf16.h>
#include <math.h>

#define BATCH 1024

typedef __attribute__((ext_vector_type(8))) short bf16x8;
typedef __attribute__((ext_vector_type(4))) float f32x4;

// Padded NHWC activation geometry: [34 rows][34 cols][64 ci] bf16, 147968 B/img
#define IMG_ELEMS 73984
#define PIX_B 128

// ---------------- LeNet conv1 (3->6, 5x5 VALID) + ReLU + 2x2 maxpool ----------------
__global__ __launch_bounds__(256) void lenet_conv1(const float* __restrict__ x,
    const float* __restrict__ w, const float* __restrict__ bias, float* __restrict__ p1)
{
    __shared__ float img[3 * 1024];
    __shared__ float wl[450];
    __shared__ float bl[6];
    int b = blockIdx.x, t = threadIdx.x;
    for (int i = t; i < 3072; i += 256) img[i] = x[(size_t)b * 3072 + i];
    for (int i = t; i < 450; i += 256) wl[i] = w[i];
    if (t < 6) bl[t] = bias[t];
    __syncthreads();
    for (int idx = t; idx < 1176; idx += 256) {
        int o = idx / 196, r = idx - o * 196, py = r / 14, px = r - py * 14;
        int y0 = 2 * py, x0 = 2 * px;
        float s00, s01, s10, s11;
        s00 = s01 = s10 = s11 = bl[o];
        for (int c = 0; c < 3; c++) {
            float pv[6][6];
            #pragma unroll
            for (int i2 = 0; i2 < 6; i2++)
                #pragma unroll
                for (int j2 = 0; j2 < 6; j2++)
                    pv[i2][j2] = img[c * 1024 + (y0 + i2) * 32 + x0 + j2];
            const float* wc = &wl[o * 75 + c * 25];
            #pragma unroll
            for (int ky = 0; ky < 5; ky++)
                #pragma unroll
                for (int kx = 0; kx < 5; kx++) {
                    float wv = wc[ky * 5 + kx];
                    s00 += pv[ky][kx] * wv;
                    s01 += pv[ky][kx + 1] * wv;
                    s10 += pv[ky + 1][kx] * wv;
                    s11 += pv[ky + 1][kx + 1] * wv;
                }
        }
        float m = fmaxf(fmaxf(s00, s01), fmaxf(s10, s11));
        p1[(size_t)b * 1176 + idx] = fmaxf(m, 0.f);
    }
}

// ---------------- LeNet conv2 (6->16, 5x5 VALID) + ReLU + 2x2 maxpool ----------------
__global__ __launch_bounds__(256) void lenet_conv2(const float* __restrict__ p1,
    const float* __restrict__ w, const float* __restrict__ bias, float* __restrict__ p2)
{
    __shared__ float img[1176];
    __shared__ float wl[2400];
    __shared__ float bl[16];
    int b = blockIdx.x, t = threadIdx.x;
    for (int i = t; i < 1176; i += 256) img[i] = p1[(size_t)b * 1176 + i];
    for (int i = t; i < 2400; i += 256) wl[i] = w[i];
    if (t < 16) bl[t] = bias[t];
    __syncthreads();
    for (int idx = t; idx < 400; idx += 256) {
        int o = idx / 25, r = idx - o * 25, py = r / 5, px = r - py * 5;
        int y0 = 2 * py, x0 = 2 * px;
        float s00, s01, s10, s11;
        s00 = s01 = s10 = s11 = bl[o];
        for (int c = 0; c < 6; c++) {
            float pv[6][6];
            #pragma unroll
            for (int i2 = 0; i2 < 6; i2++)
                #pragma unroll
                for (int j2 = 0; j2 < 6; j2++)
                    pv[i2][j2] = img[c * 196 + (y0 + i2) * 14 + x0 + j2];
            const float* wc = &wl[o * 150 + c * 25];
            #pragma unroll
            for (int ky = 0; ky < 5; ky++)
                #pragma unroll
                for (int kx = 0; kx < 5; kx++) {
                    float wv = wc[ky * 5 + kx];
                    s00 += pv[ky][kx] * wv;
                    s01 += pv[ky][kx + 1] * wv;
                    s10 += pv[ky + 1][kx] * wv;
                    s11 += pv[ky + 1][kx + 1] * wv;
                }
        }
        float m = fmaxf(fmaxf(s00, s01), fmaxf(s10, s11));
        p2[(size_t)b * 400 + idx] = fmaxf(m, 0.f);
    }
}

// ---------------- LeNet FC head + argmax + conf-matrix + low-conf flag ----------------
__global__ __launch_bounds__(128) void lenet_fc(const float* __restrict__ p2,
    const float* __restrict__ w1, const float* __restrict__ b1,
    const float* __restrict__ w2, const float* __restrict__ b2,
    const float* __restrict__ w3, const float* __restrict__ b3,
    const int* __restrict__ labels, const float* __restrict__ thr,
    float* __restrict__ out, float* __restrict__ conf, int* __restrict__ flags)
{
    __shared__ float xin[400];
    __shared__ float h1[120];
    __shared__ float h2[84];
    __shared__ float lg[10];
    int b = blockIdx.x, t = threadIdx.x;
    for (int i = t; i < 400; i += 128) xin[i] = p2[(size_t)b * 400 + i];
    __syncthreads();
    if (t < 120) {
        float s = b1[t];
        for (int k = 0; k < 400; k++) s += xin[k] * w1[k * 120 + t];
        h1[t] = fmaxf(s, 0.f);
    }
    __syncthreads();
    if (t < 84) {
        float s = b2[t];
        for (int k = 0; k < 120; k++) s += h1[k] * w2[k * 84 + t];
        h2[t] = fmaxf(s, 0.f);
    }
    __syncthreads();
    if (t < 10) {
        float s = b3[t];
        for (int k = 0; k < 84; k++) s += h2[k] * w3[k * 10 + t];
        lg[t] = s;
        out[(size_t)b * 10 + t] = s;
    }
    __syncthreads();
    if (t == 0) {
        int pred = 0;
        float m = lg[0];
        #pragma unroll
        for (int j = 1; j < 10; j++) if (lg[j] > m) { m = lg[j]; pred = j; }
        float se = 0.f, m2 = -1e30f;
        #pragma unroll
        for (int j = 0; j < 10; j++) {
            se += expf(lg[j] - m);
            if (j != pred) m2 = fmaxf(m2, lg[j]);
        }
        float gap = (1.f - expf(m2 - m)) / se;
        flags[b] = (gap <= thr[0]) ? 1 : 0;
        atomicAdd(&conf[labels[b] * 10 + pred], 1.f);
    }
}

// ---------------- weight prep: 4x OIHW fp32 [64][64][3][3] -> bf16 [tap][co][ci] ----------------
__global__ __launch_bounds__(256) void prep_weights(
    const float* __restrict__ w0, const float* __restrict__ w1,
    const float* __restrict__ w2, const float* __restrict__ w3,
    __hip_bfloat16* __restrict__ dst)
{
    int tid = blockIdx.x * 256 + threadIdx.x;
    if (tid >= 4 * 36864) return;
    int c = tid / 36864, r = tid - c * 36864;
    int tap = r / 4096, r2 = r - tap * 4096;
    int co = r2 >> 6, ci = r2 & 63;
    const float* src = (c == 0) ? w0 : (c == 1) ? w1 : (c == 2) ? w2 : w3;
    float v = src[((size_t)co * 64 + ci) * 9 + tap];
    dst[tid] = __float2bfloat16(v);
}

// ---------------- zero pad borders of [cb][34][34][64] bf16 buffer ----------------
__global__ __launch_bounds__(256) void zero_borders(__hip_bfloat16* __restrict__ buf, int cb)
{
    int tid = blockIdx.x * 256 + threadIdx.x;
    int total = cb * 132 * 8;           // 132 border px/img, 8 x 16B chunks/px
    if (tid >= total) return;
    int img = tid / 1056, r = tid - img * 1056;
    int pxi = r >> 3, chunk = r & 7;
    int pix;
    if (pxi < 34)       pix = pxi;                       // row 0
    else if (pxi < 68)  pix = 33 * 34 + (pxi - 34);      // row 33
    else if (pxi < 100) pix = (pxi - 68 + 1) * 34;       // col 0
    else                pix = (pxi - 100 + 1) * 34 + 33; // col 33
    uint4 z = {0, 0, 0, 0};
    *(uint4*)((char*)buf + (size_t)img * 147968 + pix * PIX_B + chunk * 16) = z;
}

// ---------------- conv0: NCHW fp32 [3][32][32] -> padded NHWC bf16, bias+ReLU ----------------
__global__ __launch_bounds__(256) void conv0_nhwc(const float* __restrict__ x,
    const float* __restrict__ w, const float* __restrict__ bias,
    __hip_bfloat16* __restrict__ out, int cb)
{
    __shared__ float sl[3][10][34];   // rows r0-1..r0+8, cols -1..32
    __shared__ float wl[1728];        // [64co][3ci][3][3]
    __shared__ float bl[64];
    int bid = blockIdx.x;
    int img = bid % cb, strip = bid / cb;
    int r0 = strip * 8;
    int t = threadIdx.x;
    const float* xi = x + (size_t)img * 3072;
    for (int i = t; i < 1020; i += 256) {
        int c = i / 340, rr2 = i - c * 340;
        int rr = rr2 / 34, cc = rr2 - rr * 34;
        int y = r0 + rr - 1, xx = cc - 1;
        float v = 0.f;
        if (y >= 0 && y < 32 && xx >= 0 && xx < 32) v = xi[c * 1024 + y * 32 + xx];
        sl[c][rr][cc] = v;
    }
    for (int i = t; i < 1728; i += 256) wl[i] = w[i];
    if (t < 64) bl[t] = bias[t];
    __syncthreads();

    int rr = t >> 5, col = t & 31;    // output row r0+rr, col
    float iv[27];
    #pragma unroll
    for (int c = 0; c < 3; c++)
        #pragma unroll
        for (int dy = 0; dy < 3; dy++)
            #pragma unroll
            for (int dx = 0; dx < 3; dx++)
                iv[c * 9 + dy * 3 + dx] = sl[c][rr + dy][col + dx];

    __hip_bfloat16 ov[64];
    #pragma unroll 4
    for (int co = 0; co < 64; co++) {
        float s = bl[co];
        const float* wc = &wl[co * 27];
        #pragma unroll
        for (int k = 0; k < 27; k++) s += iv[k] * wc[k];
        ov[co] = __float2bfloat16(fmaxf(s, 0.f));
    }
    int pix = (r0 + rr + 1) * 34 + (col + 1);
    uint4* dst = (uint4*)((char*)out + (size_t)img * 147968 + pix * PIX_B);
    const uint4* srcv = (const uint4*)ov;
    #pragma unroll
    for (int j = 0; j < 8; j++) dst[j] = srcv[j];
}

// ---------------- 3x3 SAME conv as implicit GEMM on MFMA, no LDS ----------------
// grid = cb*4 blocks (img = bid % cb -> 4 strips of an image share an XCD),
// 256 thr = 4 waves. Wave w: rows 2w,2w+1 of its 8-row strip.
// Per wave: 4 M-tiles (16 px) x 4 N-tiles (16 co), acc 4x4x4 VGPR.
// K-loop: 18 steps = 9 taps x 2 ci-halves; per step 4 A + 4 B global
// dwordx4 loads (uniform byte offsets; zero-padded NHWC makes taps maskless)
// + 16 mfma_f32_16x16x32_bf16. Software prefetch one step ahead.
template<bool ADD>
__global__ __launch_bounds__(256) void conv3x3_mfma(
    const __hip_bfloat16* __restrict__ act, const __hip_bfloat16* __restrict__ wts,
    const float* __restrict__ bias, const __hip_bfloat16* __restrict__ skip,
    __hip_bfloat16* __restrict__ out, int cb)
{
    int bid = blockIdx.x;
    int img = bid % cb, strip = bid / cb;
    int t = threadIdx.x;
    int w = t >> 6, lane = t & 63;
    int m = lane & 15, q = lane >> 4;

    const char* aimg = (const char*)act + (size_t)img * 147968;
    int abase[4];
    #pragma unroll
    for (int mt = 0; mt < 4; mt++) {
        int row = strip * 8 + 2 * w + (mt >> 1);
        int x0 = (mt & 1) * 16;
        abase[mt] = ((row + 1) * 34 + (x0 + 1 + m)) * PIX_B + q * 16;
    }
    const char* wb = (const char*)wts;
    int bbase[4];
    #pragma unroll
    for (int nt = 0; nt < 4; nt++)
        bbase[nt] = (nt * 16 + m) * 128 + q * 16;

    f32x4 acc[4][4] = {};
    bf16x8 a[2][4], b[2][4];

    #define LOADSTEP(s, buf)                                                   \
        {                                                                      \
            const int tap_ = (s) >> 1, kb_ = (s) & 1;                          \
            const int dy_ = tap_ / 3, dx_ = tap_ - dy_ * 3;                    \
            const int aoff_ = ((dy_ - 1) * 34 + (dx_ - 1)) * PIX_B + kb_ * 64; \
            const int boff_ = tap_ * 8192 + kb_ * 64;                          \
            _Pragma("unroll")                                                  \
            for (int mt = 0; mt < 4; mt++)                                     \
                a[buf][mt] = *(const bf16x8*)(aimg + abase[mt] + aoff_);       \
            _Pragma("unroll")                                                  \
            for (int nt = 0; nt < 4; nt++)                                     \
                b[buf][nt] = *(const bf16x8*)(wb + bbase[nt] + boff_);         \
        }

    LOADSTEP(0, 0)
    #pragma unroll
    for (int s = 0; s < 18; s++) {
        int cur = s & 1;
        if (s < 17) LOADSTEP(s + 1, cur ^ 1)
        #pragma unroll
        for (int mt = 0; mt < 4; mt++)
            #pragma unroll
            for (int nt = 0; nt < 4; nt++)
                acc[mt][nt] = __builtin_amdgcn_mfma_f32_16x16x32_bf16(
                    a[cur][mt], b[cur][nt], acc[mt][nt], 0, 0, 0);
    }
    #undef LOADSTEP

    // Epilogue: D col = lane&15 (co within N-tile), row = q*4+r (px within M-tile)
    char* oimg = (char*)out + (size_t)img * 147968;
    const char* simg = (const char*)skip + (size_t)img * 147968;
    #pragma unroll
    for (int nt = 0; nt < 4; nt++) {
        float bv = bias[nt * 16 + m];
        #pragma unroll
        for (int mt = 0; mt < 4; mt++) {
            int row = strip * 8 + 2 * w + (mt >> 1);
            int xb = (mt & 1) * 16 + q * 4;
            #pragma unroll
            for (int r = 0; r < 4; r++) {
                int off = ((row + 1) * 34 + (xb + r + 1)) * PIX_B + (nt * 16 + m) * 2;
                float v = acc[mt][nt][r] + bv;
                if (ADD) v += __bfloat162float(*(const __hip_bfloat16*)(simg + off));
                v = fmaxf(v, 0.f);
                *(__hip_bfloat16*)(oimg + off) = __float2bfloat16(v);
            }
        }
    }
}

// ---------------- ResNet head: global avg pool (bf16 NHWC padded) + FC, masked merge ----------------
__global__ __launch_bounds__(256) void res_head_bf16(const __hip_bfloat16* __restrict__ h,
    const float* __restrict__ rfc, const float* __restrict__ rfb,
    const int* __restrict__ flags, float* __restrict__ out)
{
    __shared__ float part[4][64];
    __shared__ float mns[64];
    int img = blockIdx.x, t = threadIdx.x;
    int ci = t & 63, p = t >> 6;
    const __hip_bfloat16* base = h + (size_t)img * IMG_ELEMS;
    float s = 0.f;
    for (int ry = 0; ry < 8; ry++) {
        int row = p * 8 + ry + 1;
        #pragma unroll 4
        for (int cx = 1; cx <= 32; cx++)
            s += __bfloat162float(base[(size_t)(row * 34 + cx) * 64 + ci]);
    }
    part[p][ci] = s;
    __syncthreads();
    if (t < 64) mns[t] = (part[0][t] + part[1][t] + part[2][t] + part[3][t]) * (1.f / 1024.f);
    __syncthreads();
    if (t < 10 && flags[img]) {
        float s2 = rfb[t];
        for (int c = 0; c < 64; c++) s2 += mns[c] * rfc[c * 10 + t];
        out[(size_t)img * 10 + t] = s2;
    }
}

extern "C" void kernel_launch(void* const* d_in, const int* in_sizes, int n_in,
                              void* d_out, int out_size, void* d_ws, size_t ws_size,
                              hipStream_t stream)
{
    const float* x    = (const float*)d_in[0];
    const float* thr  = (const float*)d_in[1];
    const int*   labels = (const int*)d_in[2];
    const float* lw1 = (const float*)d_in[3];  const float* lb1 = (const float*)d_in[4];
    const float* lw2 = (const float*)d_in[5];  const float* lb2 = (const float*)d_in[6];
    const float* lfc1 = (const float*)d_in[7]; const float* lfb1 = (const float*)d_in[8];
    const float* lfc2 = (const float*)d_in[9]; const float* lfb2 = (const float*)d_in[10];
    const float* lfc3 = (const float*)d_in[11];const float* lfb3 = (const float*)d_in[12];
    const float* rw0 = (const float*)d_in[13]; const float* rb0 = (const float*)d_in[14];
    const float* rw1a = (const float*)d_in[15];const float* rb1a = (const float*)d_in[16];
    const float* rw1b = (const float*)d_in[17];const float* rb1b = (const float*)d_in[18];
    const float* rw2a = (const float*)d_in[19];const float* rb2a = (const float*)d_in[20];
    const float* rw2b = (const float*)d_in[21];const float* rb2b = (const float*)d_in[22];
    const float* rfc = (const float*)d_in[23]; const float* rfb = (const float*)d_in[24];

    float* out  = (float*)d_out;
    float* conf = out + (size_t)BATCH * 10;

    // Chunking: two padded bf16 activation buffers of cb images + prepped
    // weights + flags must fit in ws_size.
    int nc = 1;
    while (nc < 16 &&
           2ull * (size_t)(BATCH / nc) * 147968ull + 294912ull + 4096ull > ws_size)
        nc <<= 1;
    int cb = BATCH / nc;

    __hip_bfloat16* A  = (__hip_bfloat16*)d_ws;
    __hip_bfloat16* Bb = A + (size_t)cb * IMG_ELEMS;
    __hip_bfloat16* wprep = Bb + (size_t)cb * IMG_ELEMS;   // 4*36864 elems
    int* flags = (int*)((char*)wprep + 294912);

    // LeNet temporaries alias the A buffer (dead before conv0 writes A)
    float* p1 = (float*)A;          // [B,6,14,14]
    float* p2 = p1 + 1204224;       // [B,400]

    hipMemsetAsync(conf, 0, 100 * sizeof(float), stream);

    prep_weights<<<(4 * 36864 + 255) / 256, 256, 0, stream>>>(rw1a, rw1b, rw2a, rw2b, wprep);

    lenet_conv1<<<BATCH, 256, 0, stream>>>(x, lw1, lb1, p1);
    lenet_conv2<<<BATCH, 256, 0, stream>>>(p1, lw2, lb2, p2);
    lenet_fc<<<BATCH, 128, 0, stream>>>(p2, lfc1, lfb1, lfc2, lfb2, lfc3, lfb3,
                                        labels, thr, out, conf, flags);

    // Borders of both activation buffers: zero once (convs only write interiors)
    int zb = (cb * 1056 + 255) / 256;
    zero_borders<<<zb, 256, 0, stream>>>(A, cb);
    zero_borders<<<zb, 256, 0, stream>>>(Bb, cb);

    const __hip_bfloat16* W1a = wprep;
    const __hip_bfloat16* W1b = wprep + 36864;
    const __hip_bfloat16* W2a = wprep + 2 * 36864;
    const __hip_bfloat16* W2b = wprep + 3 * 36864;

    for (int c0 = 0; c0 < BATCH; c0 += cb) {
        const float* xc = x + (size_t)c0 * 3072;
        conv0_nhwc<<<cb * 4, 256, 0, stream>>>(xc, rw0, rb0, A, cb);
        conv3x3_mfma<false><<<cb * 4, 256, 0, stream>>>(A,  W1a, rb1a, nullptr, Bb, cb);
        conv3x3_mfma<true ><<<cb * 4, 256, 0, stream>>>(Bb, W1b, rb1b, A, A, cb);
        conv3x3_mfma<false><<<cb * 4, 256, 0, stream>>>(A,  W2a, rb2a, nullptr, Bb, cb);
        conv3x3_mfma<true ><<<cb * 4, 256, 0, stream>>>(Bb, W2b, rb2b, A, A, cb);
        res_head_bf16<<<cb, 256, 0, stream>>>(A, rfc, rfb, flags + c0, out + (size_t)c0 * 10);
    }
}

// Round 4
// 1220.662 us; speedup vs baseline: 7.6553x; 1.2424x over previous
//
#include <hip/hip_runtime.h>
#include <hip/hip_bf16.h>
#include <math.h>

#define BATCH 1024

typedef __attribute__((ext_vector_type(8))) short bf16x8;
typedef __attribute__((ext_vector_type(4))) float f32x4;

// Padded NHWC activation geometry: [34 rows][34 cols][64 ci] bf16, 147968 B/img
#define IMG_ELEMS 73984
#define PIX_B 128
#define ROW_B 4352            // 34 * 128
// LDS tile geometry: 10 rows x 34 px, pixel stride 144 B (conflict-free b128)
#define LPIX_B 144
#define LROW_B 4896           // 34 * 144

// ---------------- LeNet conv1 (3->6, 5x5 VALID) + ReLU + 2x2 maxpool ----------------
__global__ __launch_bounds__(256) void lenet_conv1(const float* __restrict__ x,
    const float* __restrict__ w, const float* __restrict__ bias, float* __restrict__ p1)
{
    __shared__ float img[3 * 1024];
    __shared__ float wl[450];
    __shared__ float bl[6];
    int b = blockIdx.x, t = threadIdx.x;
    for (int i = t; i < 3072; i += 256) img[i] = x[(size_t)b * 3072 + i];
    for (int i = t; i < 450; i += 256) wl[i] = w[i];
    if (t < 6) bl[t] = bias[t];
    __syncthreads();
    for (int idx = t; idx < 1176; idx += 256) {
        int o = idx / 196, r = idx - o * 196, py = r / 14, px = r - py * 14;
        int y0 = 2 * py, x0 = 2 * px;
        float s00, s01, s10, s11;
        s00 = s01 = s10 = s11 = bl[o];
        for (int c = 0; c < 3; c++) {
            float pv[6][6];
            #pragma unroll
            for (int i2 = 0; i2 < 6; i2++)
                #pragma unroll
                for (int j2 = 0; j2 < 6; j2++)
                    pv[i2][j2] = img[c * 1024 + (y0 + i2) * 32 + x0 + j2];
            const float* wc = &wl[o * 75 + c * 25];
            #pragma unroll
            for (int ky = 0; ky < 5; ky++)
                #pragma unroll
                for (int kx = 0; kx < 5; kx++) {
                    float wv = wc[ky * 5 + kx];
                    s00 += pv[ky][kx] * wv;
                    s01 += pv[ky][kx + 1] * wv;
                    s10 += pv[ky + 1][kx] * wv;
                    s11 += pv[ky + 1][kx + 1] * wv;
                }
        }
        float m = fmaxf(fmaxf(s00, s01), fmaxf(s10, s11));
        p1[(size_t)b * 1176 + idx] = fmaxf(m, 0.f);
    }
}

// ---------------- LeNet conv2 (6->16, 5x5 VALID) + ReLU + 2x2 maxpool ----------------
__global__ __launch_bounds__(256) void lenet_conv2(const float* __restrict__ p1,
    const float* __restrict__ w, const float* __restrict__ bias, float* __restrict__ p2)
{
    __shared__ float img[1176];
    __shared__ float wl[2400];
    __shared__ float bl[16];
    int b = blockIdx.x, t = threadIdx.x;
    for (int i = t; i < 1176; i += 256) img[i] = p1[(size_t)b * 1176 + i];
    for (int i = t; i < 2400; i += 256) wl[i] = w[i];
    if (t < 16) bl[t] = bias[t];
    __syncthreads();
    for (int idx = t; idx < 400; idx += 256) {
        int o = idx / 25, r = idx - o * 25, py = r / 5, px = r - py * 5;
        int y0 = 2 * py, x0 = 2 * px;
        float s00, s01, s10, s11;
        s00 = s01 = s10 = s11 = bl[o];
        for (int c = 0; c < 6; c++) {
            float pv[6][6];
            #pragma unroll
            for (int i2 = 0; i2 < 6; i2++)
                #pragma unroll
                for (int j2 = 0; j2 < 6; j2++)
                    pv[i2][j2] = img[c * 196 + (y0 + i2) * 14 + x0 + j2];
            const float* wc = &wl[o * 150 + c * 25];
            #pragma unroll
            for (int ky = 0; ky < 5; ky++)
                #pragma unroll
                for (int kx = 0; kx < 5; kx++) {
                    float wv = wc[ky * 5 + kx];
                    s00 += pv[ky][kx] * wv;
                    s01 += pv[ky][kx + 1] * wv;
                    s10 += pv[ky + 1][kx] * wv;
                    s11 += pv[ky + 1][kx + 1] * wv;
                }
        }
        float m = fmaxf(fmaxf(s00, s01), fmaxf(s10, s11));
        p2[(size_t)b * 400 + idx] = fmaxf(m, 0.f);
    }
}

// ---------------- LeNet FC head + argmax + conf-matrix + low-conf flag ----------------
__global__ __launch_bounds__(256) void lenet_fc(const float* __restrict__ p2,
    const float* __restrict__ w1, const float* __restrict__ b1,
    const float* __restrict__ w2, const float* __restrict__ b2,
    const float* __restrict__ w3, const float* __restrict__ b3,
    const int* __restrict__ labels, const float* __restrict__ thr,
    float* __restrict__ out, float* __restrict__ conf, int* __restrict__ flags)
{
    __shared__ float xin[400];
    __shared__ float h1[120];
    __shared__ float h2[84];
    __shared__ float ps[256];
    __shared__ float lg[10];
    int b = blockIdx.x, t = threadIdx.x;
    for (int i = t; i < 400; i += 256) xin[i] = p2[(size_t)b * 400 + i];
    __syncthreads();
    {
        int n = t & 127, half = t >> 7;
        float s = 0.f;
        if (n < 120) {
            int k0 = half * 200;
            for (int k = k0; k < k0 + 200; k++) s += xin[k] * w1[k * 120 + n];
        }
        ps[t] = s;
    }
    __syncthreads();
    if (t < 120) h1[t] = fmaxf(ps[t] + ps[t + 128] + b1[t], 0.f);
    __syncthreads();
    {
        int n = t & 127, half = t >> 7;
        float s = 0.f;
        if (n < 84) {
            int k0 = half * 60;
            for (int k = k0; k < k0 + 60; k++) s += h1[k] * w2[k * 84 + n];
        }
        ps[t] = s;
    }
    __syncthreads();
    if (t < 84) h2[t] = fmaxf(ps[t] + ps[t + 128] + b2[t], 0.f);
    __syncthreads();
    if (t < 10) {
        float s = b3[t];
        for (int k = 0; k < 84; k++) s += h2[k] * w3[k * 10 + t];
        lg[t] = s;
        out[(size_t)b * 10 + t] = s;
    }
    __syncthreads();
    if (t == 0) {
        int pred = 0;
        float m = lg[0];
        #pragma unroll
        for (int j = 1; j < 10; j++) if (lg[j] > m) { m = lg[j]; pred = j; }
        float se = 0.f, m2 = -1e30f;
        #pragma unroll
        for (int j = 0; j < 10; j++) {
            se += expf(lg[j] - m);
            if (j != pred) m2 = fmaxf(m2, lg[j]);
        }
        float gap = (1.f - expf(m2 - m)) / se;
        flags[b] = (gap <= thr[0]) ? 1 : 0;
        atomicAdd(&conf[labels[b] * 10 + pred], 1.f);
    }
}

// ---------------- weight prep: 4x OIHW fp32 [64][64][3][3] -> bf16 [tap][co][ci] ----------------
__global__ __launch_bounds__(256) void prep_weights(
    const float* __restrict__ w0, const float* __restrict__ w1,
    const float* __restrict__ w2, const float* __restrict__ w3,
    __hip_bfloat16* __restrict__ dst)
{
    int tid = blockIdx.x * 256 + threadIdx.x;
    if (tid >= 4 * 36864) return;
    int c = tid / 36864, r = tid - c * 36864;
    int tap = r / 4096, r2 = r - tap * 4096;
    int co = r2 >> 6, ci = r2 & 63;
    const float* src = (c == 0) ? w0 : (c == 1) ? w1 : (c == 2) ? w2 : w3;
    float v = src[((size_t)co * 64 + ci) * 9 + tap];
    dst[tid] = __float2bfloat16(v);
}

// ---------------- zero pad borders of [cb][34][34][64] bf16 buffer ----------------
__global__ __launch_bounds__(256) void zero_borders(__hip_bfloat16* __restrict__ buf, int cb)
{
    int tid = blockIdx.x * 256 + threadIdx.x;
    int total = cb * 132 * 8;
    if (tid >= total) return;
    int img = tid / 1056, r = tid - img * 1056;
    int pxi = r >> 3, chunk = r & 7;
    int pix;
    if (pxi < 34)       pix = pxi;
    else if (pxi < 68)  pix = 33 * 34 + (pxi - 34);
    else if (pxi < 100) pix = (pxi - 68 + 1) * 34;
    else                pix = (pxi - 100 + 1) * 34 + 33;
    uint4 z = {0, 0, 0, 0};
    *(uint4*)((char*)buf + (size_t)img * 147968 + pix * PIX_B + chunk * 16) = z;
}

// ---------------- conv0: NCHW fp32 [3][32][32] -> padded NHWC bf16, bias+ReLU ----------------
__global__ __launch_bounds__(256) void conv0_nhwc(const float* __restrict__ x,
    const float* __restrict__ w, const float* __restrict__ bias,
    __hip_bfloat16* __restrict__ out, int cb)
{
    __shared__ float sl[3][10][34];
    __shared__ float wl[1728];
    __shared__ float bl[64];
    int bid = blockIdx.x;
    int img = bid % cb, strip = bid / cb;
    int r0 = strip * 8;
    int t = threadIdx.x;
    const float* xi = x + (size_t)img * 3072;
    for (int i = t; i < 1020; i += 256) {
        int c = i / 340, rr2 = i - c * 340;
        int rr = rr2 / 34, cc = rr2 - rr * 34;
        int y = r0 + rr - 1, xx = cc - 1;
        float v = 0.f;
        if (y >= 0 && y < 32 && xx >= 0 && xx < 32) v = xi[c * 1024 + y * 32 + xx];
        sl[c][rr][cc] = v;
    }
    for (int i = t; i < 1728; i += 256) wl[i] = w[i];
    if (t < 64) bl[t] = bias[t];
    __syncthreads();

    int rr = t >> 5, col = t & 31;
    float iv[27];
    #pragma unroll
    for (int c = 0; c < 3; c++)
        #pragma unroll
        for (int dy = 0; dy < 3; dy++)
            #pragma unroll
            for (int dx = 0; dx < 3; dx++)
                iv[c * 9 + dy * 3 + dx] = sl[c][rr + dy][col + dx];

    __hip_bfloat16 ov[64];
    #pragma unroll 4
    for (int co = 0; co < 64; co++) {
        float s = bl[co];
        const float* wc = &wl[co * 27];
        #pragma unroll
        for (int k = 0; k < 27; k++) s += iv[k] * wc[k];
        ov[co] = __float2bfloat16(fmaxf(s, 0.f));
    }
    int pix = (r0 + rr + 1) * 34 + (col + 1);
    uint4* dst = (uint4*)((char*)out + (size_t)img * 147968 + pix * PIX_B);
    const uint4* srcv = (const uint4*)ov;
    #pragma unroll
    for (int j = 0; j < 8; j++) dst[j] = srcv[j];
}

// ---------------- 3x3 SAME conv: implicit GEMM, A staged in LDS ----------------
// grid = cb*4 (img-major), block = 256 thr / 4 waves, strip of 8 output rows.
// LDS: 10 padded rows x 34 px x 64 ci bf16, pixel stride 144 B -> every wave64
// ds_read_b128 touches each bank exactly 8x (the minimum) -> conflict-free.
// Staged ONCE per block (one barrier total); K-loop: 18 steps x (4 A ds_read
// + 4 B global dwordx4 + 16 MFMA), both operands double-buffered.
template<bool ADD>
__global__ __launch_bounds__(256) void conv3x3_lds(
    const __hip_bfloat16* __restrict__ act, const __hip_bfloat16* __restrict__ wts,
    const float* __restrict__ bias, const __hip_bfloat16* __restrict__ skip,
    __hip_bfloat16* __restrict__ out, int cb)
{
    __shared__ char sl[10 * LROW_B];   // 48960 B -> 3 blocks/CU
    int bid = blockIdx.x;
    int img = bid % cb, strip = bid / cb;
    int t = threadIdx.x;
    int w = t >> 6, lane = t & 63;
    int m = lane & 15, q = lane >> 4;

    // ---- stage 10 padded rows (global rows strip*8 .. strip*8+9) ----
    const char* gsrc = (const char*)act + (size_t)img * 147968 + (size_t)(strip * 8) * ROW_B;
    for (int i = t; i < 340; i += 256) {
        int r = i / 34, c = i - r * 34;
        const uint4* s = (const uint4*)(gsrc + r * ROW_B + c * PIX_B);
        char* d = sl + r * LROW_B + c * LPIX_B;
        #pragma unroll
        for (int j = 0; j < 8; j++) *(uint4*)(d + j * 16) = s[j];
    }
    __syncthreads();

    // ---- fragment base offsets ----
    int abase[4];
    #pragma unroll
    for (int mt = 0; mt < 4; mt++)
        abase[mt] = (2 * w + (mt >> 1)) * LROW_B + ((mt & 1) * 16 + m) * LPIX_B + q * 16;
    const char* wb = (const char*)wts;
    int bbase[4];
    #pragma unroll
    for (int nt = 0; nt < 4; nt++)
        bbase[nt] = (nt * 16 + m) * 128 + q * 16;

    f32x4 acc[4][4] = {};
    bf16x8 a[2][4], b[2][4];

    #define LOADSTEP(s, buf)                                                   \
        {                                                                      \
            const int tap_ = (s) >> 1, kb_ = (s) & 1;                          \
            const int dy_ = tap_ / 3, dx_ = tap_ - dy_ * 3;                    \
            const int aoff_ = dy_ * LROW_B + dx_ * LPIX_B + kb_ * 64;          \
            const int boff_ = tap_ * 8192 + kb_ * 64;                          \
            _Pragma("unroll")                                                  \
            for (int mt = 0; mt < 4; mt++)                                     \
                a[buf][mt] = *(const bf16x8*)(sl + abase[mt] + aoff_);         \
            _Pragma("unroll")                                                  \
            for (int nt = 0; nt < 4; nt++)                                     \
                b[buf][nt] = *(const bf16x8*)(wb + bbase[nt] + boff_);         \
        }

    LOADSTEP(0, 0)
    #pragma unroll
    for (int s = 0; s < 18; s++) {
        int cur = s & 1;
        if (s < 17) LOADSTEP(s + 1, cur ^ 1)
        #pragma unroll
        for (int mt = 0; mt < 4; mt++)
            #pragma unroll
            for (int nt = 0; nt < 4; nt++)
                acc[mt][nt] = __builtin_amdgcn_mfma_f32_16x16x32_bf16(
                    a[cur][mt], b[cur][nt], acc[mt][nt], 0, 0, 0);
    }
    #undef LOADSTEP

    // ---- epilogue: D col = lane&15 (co), row = q*4+r (px) ----
    char* oimg = (char*)out + (size_t)img * 147968;
    const char* simg = (const char*)skip + (size_t)img * 147968;
    #pragma unroll
    for (int nt = 0; nt < 4; nt++) {
        float bv = bias[nt * 16 + m];
        #pragma unroll
        for (int mt = 0; mt < 4; mt++) {
            int row = strip * 8 + 2 * w + (mt >> 1);
            int xb = (mt & 1) * 16 + q * 4;
            #pragma unroll
            for (int r = 0; r < 4; r++) {
                int off = ((row + 1) * 34 + (xb + r + 1)) * PIX_B + (nt * 16 + m) * 2;
                float v = acc[mt][nt][r] + bv;
                if (ADD) v += __bfloat162float(*(const __hip_bfloat16*)(simg + off));
                v = fmaxf(v, 0.f);
                *(__hip_bfloat16*)(oimg + off) = __float2bfloat16(v);
            }
        }
    }
}

// ---------------- ResNet head: avg pool (vectorized) + FC, masked merge ----------------
__global__ __launch_bounds__(256) void res_head_bf16(const __hip_bfloat16* __restrict__ h,
    const float* __restrict__ rfc, const float* __restrict__ rfb,
    const int* __restrict__ flags, float* __restrict__ out)
{
    __shared__ float part[4][64];
    __shared__ float mns[64];
    int img = blockIdx.x, t = threadIdx.x;
    int w = t >> 6, lane = t & 63;
    int c = lane & 7;                    // ci chunk (8 ci)
    const char* base = (const char*)h + (size_t)img * 147968;

    float s8[8];
    #pragma unroll
    for (int j = 0; j < 8; j++) s8[j] = 0.f;

    for (int ry = 0; ry < 8; ry++) {
        int row = w * 8 + ry + 1;
        const char* rb = base + row * ROW_B + PIX_B;   // col 1
        #pragma unroll
        for (int k = 0; k < 4; k++) {
            // chunk g = lane + 64*k in [0,256): px = g>>3, ci-chunk = g&7 (= c)
            int g = lane + 64 * k;
            bf16x8 v = *(const bf16x8*)(rb + (g >> 3) * PIX_B + c * 16);
            #pragma unroll
            for (int j = 0; j < 8; j++)
                s8[j] += __bfloat162float(*(__hip_bfloat16*)&((short*)&v)[j]);
        }
    }
    // reduce over px-slot lanes (bits 3,4,5)
    #pragma unroll
    for (int off = 8; off <= 32; off <<= 1)
        #pragma unroll
        for (int j = 0; j < 8; j++) s8[j] += __shfl_xor(s8[j], off, 64);
    if (lane < 8)
        #pragma unroll
        for (int j = 0; j < 8; j++) part[w][c * 8 + j] = s8[j];
    __syncthreads();
    if (t < 64) mns[t] = (part[0][t] + part[1][t] + part[2][t] + part[3][t]) * (1.f / 1024.f);
    __syncthreads();
    if (t < 10 && flags[img]) {
        float s2 = rfb[t];
        for (int cc = 0; cc < 64; cc++) s2 += mns[cc] * rfc[cc * 10 + t];
        out[(size_t)img * 10 + t] = s2;
    }
}

extern "C" void kernel_launch(void* const* d_in, const int* in_sizes, int n_in,
                              void* d_out, int out_size, void* d_ws, size_t ws_size,
                              hipStream_t stream)
{
    const float* x    = (const float*)d_in[0];
    const float* thr  = (const float*)d_in[1];
    const int*   labels = (const int*)d_in[2];
    const float* lw1 = (const float*)d_in[3];  const float* lb1 = (const float*)d_in[4];
    const float* lw2 = (const float*)d_in[5];  const float* lb2 = (const float*)d_in[6];
    const float* lfc1 = (const float*)d_in[7]; const float* lfb1 = (const float*)d_in[8];
    const float* lfc2 = (const float*)d_in[9]; const float* lfb2 = (const float*)d_in[10];
    const float* lfc3 = (const float*)d_in[11];const float* lfb3 = (const float*)d_in[12];
    const float* rw0 = (const float*)d_in[13]; const float* rb0 = (const float*)d_in[14];
    const float* rw1a = (const float*)d_in[15];const float* rb1a = (const float*)d_in[16];
    const float* rw1b = (const float*)d_in[17];const float* rb1b = (const float*)d_in[18];
    const float* rw2a = (const float*)d_in[19];const float* rb2a = (const float*)d_in[20];
    const float* rw2b = (const float*)d_in[21];const float* rb2b = (const float*)d_in[22];
    const float* rfc = (const float*)d_in[23]; const float* rfb = (const float*)d_in[24];

    float* out  = (float*)d_out;
    float* conf = out + (size_t)BATCH * 10;

    int nc = 1;
    while (nc < 16 &&
           2ull * (size_t)(BATCH / nc) * 147968ull + 294912ull + 4096ull > ws_size)
        nc <<= 1;
    int cb = BATCH / nc;

    __hip_bfloat16* A  = (__hip_bfloat16*)d_ws;
    __hip_bfloat16* Bb = A + (size_t)cb * IMG_ELEMS;
    __hip_bfloat16* wprep = Bb + (size_t)cb * IMG_ELEMS;
    int* flags = (int*)((char*)wprep + 294912);

    float* p1 = (float*)A;
    float* p2 = p1 + 1204224;

    hipMemsetAsync(conf, 0, 100 * sizeof(float), stream);

    prep_weights<<<(4 * 36864 + 255) / 256, 256, 0, stream>>>(rw1a, rw1b, rw2a, rw2b, wprep);

    lenet_conv1<<<BATCH, 256, 0, stream>>>(x, lw1, lb1, p1);
    lenet_conv2<<<BATCH, 256, 0, stream>>>(p1, lw2, lb2, p2);
    lenet_fc<<<BATCH, 256, 0, stream>>>(p2, lfc1, lfb1, lfc2, lfb2, lfc3, lfb3,
                                        labels, thr, out, conf, flags);

    int zb = (cb * 1056 + 255) / 256;
    zero_borders<<<zb, 256, 0, stream>>>(A, cb);
    zero_borders<<<zb, 256, 0, stream>>>(Bb, cb);

    const __hip_bfloat16* W1a = wprep;
    const __hip_bfloat16* W1b = wprep + 36864;
    const __hip_bfloat16* W2a = wprep + 2 * 36864;
    const __hip_bfloat16* W2b = wprep + 3 * 36864;

    for (int c0 = 0; c0 < BATCH; c0 += cb) {
        const float* xc = x + (size_t)c0 * 3072;
        conv0_nhwc<<<cb * 4, 256, 0, stream>>>(xc, rw0, rb0, A, cb);
        conv3x3_lds<false><<<cb * 4, 256, 0, stream>>>(A,  W1a, rb1a, nullptr, Bb, cb);
        conv3x3_lds<true ><<<cb * 4, 256, 0, stream>>>(Bb, W1b, rb1b, A, A, cb);
        conv3x3_lds<false><<<cb * 4, 256, 0, stream>>>(A,  W2a, rb2a, nullptr, Bb, cb);
        conv3x3_lds<true ><<<cb * 4, 256, 0, stream>>>(Bb, W2b, rb2b, A, A, cb);
        res_head_bf16<<<cb, 256, 0, stream>>>(A, rfc, rfb, flags + c0, out + (size_t)c0 * 10);
    }
}

// Round 5
// 1048.014 us; speedup vs baseline: 8.9165x; 1.1647x over previous
//
#include <hip/hip_runtime.h>
#include <hip/hip_bf16.h>
#include <math.h>

#define BATCH 1024

typedef __attribute__((ext_vector_type(8))) short bf16x8;
typedef __attribute__((ext_vector_type(4))) float f32x4;

// Padded NHWC activation geometry: [34 rows][34 cols][64 ci] bf16, 147968 B/img
#define IMG_ELEMS 73984
#define PIX_B 128
#define ROW_B 4352            // 34 * 128
// LDS tile geometry: pixel stride 144 B (conflict-free b128)
#define LPIX_B 144
#define LROW_B 4896           // 34 * 144

// ---------------- LeNet conv1 (3->6, 5x5 VALID) + ReLU + 2x2 maxpool ----------------
__global__ __launch_bounds__(256) void lenet_conv1(const float* __restrict__ x,
    const float* __restrict__ w, const float* __restrict__ bias, float* __restrict__ p1)
{
    __shared__ float img[3 * 1024];
    __shared__ float wl[450];
    __shared__ float bl[6];
    int b = blockIdx.x, t = threadIdx.x;
    for (int i = t; i < 3072; i += 256) img[i] = x[(size_t)b * 3072 + i];
    for (int i = t; i < 450; i += 256) wl[i] = w[i];
    if (t < 6) bl[t] = bias[t];
    __syncthreads();
    for (int idx = t; idx < 1176; idx += 256) {
        int o = idx / 196, r = idx - o * 196, py = r / 14, px = r - py * 14;
        int y0 = 2 * py, x0 = 2 * px;
        float s00, s01, s10, s11;
        s00 = s01 = s10 = s11 = bl[o];
        for (int c = 0; c < 3; c++) {
            float pv[6][6];
            #pragma unroll
            for (int i2 = 0; i2 < 6; i2++)
                #pragma unroll
                for (int j2 = 0; j2 < 6; j2++)
                    pv[i2][j2] = img[c * 1024 + (y0 + i2) * 32 + x0 + j2];
            const float* wc = &wl[o * 75 + c * 25];
            #pragma unroll
            for (int ky = 0; ky < 5; ky++)
                #pragma unroll
                for (int kx = 0; kx < 5; kx++) {
                    float wv = wc[ky * 5 + kx];
                    s00 += pv[ky][kx] * wv;
                    s01 += pv[ky][kx + 1] * wv;
                    s10 += pv[ky + 1][kx] * wv;
                    s11 += pv[ky + 1][kx + 1] * wv;
                }
        }
        float m = fmaxf(fmaxf(s00, s01), fmaxf(s10, s11));
        p1[(size_t)b * 1176 + idx] = fmaxf(m, 0.f);
    }
}

// ---------------- LeNet conv2 (6->16, 5x5 VALID) + ReLU + 2x2 maxpool ----------------
__global__ __launch_bounds__(256) void lenet_conv2(const float* __restrict__ p1,
    const float* __restrict__ w, const float* __restrict__ bias, float* __restrict__ p2)
{
    __shared__ float img[1176];
    __shared__ float wl[2400];
    __shared__ float bl[16];
    int b = blockIdx.x, t = threadIdx.x;
    for (int i = t; i < 1176; i += 256) img[i] = p1[(size_t)b * 1176 + i];
    for (int i = t; i < 2400; i += 256) wl[i] = w[i];
    if (t < 16) bl[t] = bias[t];
    __syncthreads();
    for (int idx = t; idx < 400; idx += 256) {
        int o = idx / 25, r = idx - o * 25, py = r / 5, px = r - py * 5;
        int y0 = 2 * py, x0 = 2 * px;
        float s00, s01, s10, s11;
        s00 = s01 = s10 = s11 = bl[o];
        for (int c = 0; c < 6; c++) {
            float pv[6][6];
            #pragma unroll
            for (int i2 = 0; i2 < 6; i2++)
                #pragma unroll
                for (int j2 = 0; j2 < 6; j2++)
                    pv[i2][j2] = img[c * 196 + (y0 + i2) * 14 + x0 + j2];
            const float* wc = &wl[o * 150 + c * 25];
            #pragma unroll
            for (int ky = 0; ky < 5; ky++)
                #pragma unroll
                for (int kx = 0; kx < 5; kx++) {
                    float wv = wc[ky * 5 + kx];
                    s00 += pv[ky][kx] * wv;
                    s01 += pv[ky][kx + 1] * wv;
                    s10 += pv[ky + 1][kx] * wv;
                    s11 += pv[ky + 1][kx + 1] * wv;
                }
        }
        float m = fmaxf(fmaxf(s00, s01), fmaxf(s10, s11));
        p2[(size_t)b * 400 + idx] = fmaxf(m, 0.f);
    }
}

// ---------------- LeNet FC head + argmax + conf-matrix + low-conf flag ----------------
__global__ __launch_bounds__(256) void lenet_fc(const float* __restrict__ p2,
    const float* __restrict__ w1, const float* __restrict__ b1,
    const float* __restrict__ w2, const float* __restrict__ b2,
    const float* __restrict__ w3, const float* __restrict__ b3,
    const int* __restrict__ labels, const float* __restrict__ thr,
    float* __restrict__ out, float* __restrict__ conf, int* __restrict__ flags)
{
    __shared__ float xin[400];
    __shared__ float h1[120];
    __shared__ float h2[84];
    __shared__ float ps[256];
    __shared__ float lg[10];
    int b = blockIdx.x, t = threadIdx.x;
    for (int i = t; i < 400; i += 256) xin[i] = p2[(size_t)b * 400 + i];
    __syncthreads();
    {
        int n = t & 127, half = t >> 7;
        float s = 0.f;
        if (n < 120) {
            int k0 = half * 200;
            for (int k = k0; k < k0 + 200; k++) s += xin[k] * w1[k * 120 + n];
        }
        ps[t] = s;
    }
    __syncthreads();
    if (t < 120) h1[t] = fmaxf(ps[t] + ps[t + 128] + b1[t], 0.f);
    __syncthreads();
    {
        int n = t & 127, half = t >> 7;
        float s = 0.f;
        if (n < 84) {
            int k0 = half * 60;
            for (int k = k0; k < k0 + 60; k++) s += h1[k] * w2[k * 84 + n];
        }
        ps[t] = s;
    }
    __syncthreads();
    if (t < 84) h2[t] = fmaxf(ps[t] + ps[t + 128] + b2[t], 0.f);
    __syncthreads();
    if (t < 10) {
        float s = b3[t];
        for (int k = 0; k < 84; k++) s += h2[k] * w3[k * 10 + t];
        lg[t] = s;
        out[(size_t)b * 10 + t] = s;
    }
    __syncthreads();
    if (t == 0) {
        int pred = 0;
        float m = lg[0];
        #pragma unroll
        for (int j = 1; j < 10; j++) if (lg[j] > m) { m = lg[j]; pred = j; }
        float se = 0.f, m2 = -1e30f;
        #pragma unroll
        for (int j = 0; j < 10; j++) {
            se += expf(lg[j] - m);
            if (j != pred) m2 = fmaxf(m2, lg[j]);
        }
        float gap = (1.f - expf(m2 - m)) / se;
        flags[b] = (gap <= thr[0]) ? 1 : 0;
        atomicAdd(&conf[labels[b] * 10 + pred], 1.f);
    }
}

// ---------------- weight prep: 4x OIHW fp32 [64][64][3][3] -> bf16 [tap][co][ci] ----------------
__global__ __launch_bounds__(256) void prep_weights(
    const float* __restrict__ w0, const float* __restrict__ w1,
    const float* __restrict__ w2, const float* __restrict__ w3,
    __hip_bfloat16* __restrict__ dst)
{
    int tid = blockIdx.x * 256 + threadIdx.x;
    if (tid >= 4 * 36864) return;
    int c = tid / 36864, r = tid - c * 36864;
    int tap = r / 4096, r2 = r - tap * 4096;
    int co = r2 >> 6, ci = r2 & 63;
    const float* src = (c == 0) ? w0 : (c == 1) ? w1 : (c == 2) ? w2 : w3;
    float v = src[((size_t)co * 64 + ci) * 9 + tap];
    dst[tid] = __float2bfloat16(v);
}

// ---------------- zero pad borders of [cb][34][34][64] bf16 buffer ----------------
__global__ __launch_bounds__(256) void zero_borders(__hip_bfloat16* __restrict__ buf, int cb)
{
    int tid = blockIdx.x * 256 + threadIdx.x;
    int total = cb * 132 * 8;
    if (tid >= total) return;
    int img = tid / 1056, r = tid - img * 1056;
    int pxi = r >> 3, chunk = r & 7;
    int pix;
    if (pxi < 34)       pix = pxi;
    else if (pxi < 68)  pix = 33 * 34 + (pxi - 34);
    else if (pxi < 100) pix = (pxi - 68 + 1) * 34;
    else                pix = (pxi - 100 + 1) * 34 + 33;
    uint4 z = {0, 0, 0, 0};
    *(uint4*)((char*)buf + (size_t)img * 147968 + pix * PIX_B + chunk * 16) = z;
}

// ---------------- conv0: NCHW fp32 [3][32][32] -> padded NHWC bf16, bias+ReLU ----------------
__global__ __launch_bounds__(256) void conv0_nhwc(const float* __restrict__ x,
    const float* __restrict__ w, const float* __restrict__ bias,
    __hip_bfloat16* __restrict__ out, int cb)
{
    __shared__ float sl[3][10][34];
    __shared__ float wl[1728];
    __shared__ float bl[64];
    int bid = blockIdx.x;
    int img = bid % cb, strip = bid / cb;
    int r0 = strip * 8;
    int t = threadIdx.x;
    const float* xi = x + (size_t)img * 3072;
    for (int i = t; i < 1020; i += 256) {
        int c = i / 340, rr2 = i - c * 340;
        int rr = rr2 / 34, cc = rr2 - rr * 34;
        int y = r0 + rr - 1, xx = cc - 1;
        float v = 0.f;
        if (y >= 0 && y < 32 && xx >= 0 && xx < 32) v = xi[c * 1024 + y * 32 + xx];
        sl[c][rr][cc] = v;
    }
    for (int i = t; i < 1728; i += 256) wl[i] = w[i];
    if (t < 64) bl[t] = bias[t];
    __syncthreads();

    int rr = t >> 5, col = t & 31;
    float iv[27];
    #pragma unroll
    for (int c = 0; c < 3; c++)
        #pragma unroll
        for (int dy = 0; dy < 3; dy++)
            #pragma unroll
            for (int dx = 0; dx < 3; dx++)
                iv[c * 9 + dy * 3 + dx] = sl[c][rr + dy][col + dx];

    __hip_bfloat16 ov[64];
    #pragma unroll 4
    for (int co = 0; co < 64; co++) {
        float s = bl[co];
        const float* wc = &wl[co * 27];
        #pragma unroll
        for (int k = 0; k < 27; k++) s += iv[k] * wc[k];
        ov[co] = __float2bfloat16(fmaxf(s, 0.f));
    }
    int pix = (r0 + rr + 1) * 34 + (col + 1);
    uint4* dst = (uint4*)((char*)out + (size_t)img * 147968 + pix * PIX_B);
    const uint4* srcv = (const uint4*)ov;
    #pragma unroll
    for (int j = 0; j < 8; j++) dst[j] = srcv[j];
}

// ---------------- 3x3 SAME conv: implicit GEMM, A in LDS, B reg-ring ----------------
// grid = cb*4 (img-major), block = 256 thr / 4 waves, strip of 8 output rows.
// LDS: 10 rows x 34 px x 64 ci bf16 @ 144 B px-stride (conflict-free b128).
// K-loop: 18 steps (9 taps x 2 ci-halves); A double-buffered from LDS,
// B (weights) in a depth-3 register ring -> ~2.5-step (~200 cyc) prefetch
// distance covers L1-miss/L2 latency. Epilogue: bias+bf16 -> LDS [px][co]
// bounce -> fully coalesced dwordx4 skip-load/add/relu/store.
template<bool ADD>
__global__ __launch_bounds__(256, 3) void conv3x3_lds(
    const __hip_bfloat16* __restrict__ act, const __hip_bfloat16* __restrict__ wts,
    const float* __restrict__ bias, const __hip_bfloat16* __restrict__ skip,
    __hip_bfloat16* __restrict__ out, int cb)
{
    __shared__ char sl[10 * LROW_B];   // 48960 B -> 3 blocks/CU
    int bid = blockIdx.x;
    int img = bid % cb, strip = bid / cb;
    int t = threadIdx.x;
    int w = t >> 6, lane = t & 63;
    int m = lane & 15, q = lane >> 4;

    // ---- stage 10 padded rows (global padded rows strip*8 .. strip*8+9) ----
    const char* gsrc = (const char*)act + (size_t)img * 147968 + (size_t)(strip * 8) * ROW_B;
    for (int i = t; i < 340; i += 256) {
        int r = i / 34, c = i - r * 34;
        const uint4* s = (const uint4*)(gsrc + r * ROW_B + c * PIX_B);
        char* d = sl + r * LROW_B + c * LPIX_B;
        #pragma unroll
        for (int j = 0; j < 8; j++) *(uint4*)(d + j * 16) = s[j];
    }
    __syncthreads();

    // ---- fragment base offsets ----
    int abase[4];
    #pragma unroll
    for (int mt = 0; mt < 4; mt++)
        abase[mt] = (2 * w + (mt >> 1)) * LROW_B + ((mt & 1) * 16 + m) * LPIX_B + q * 16;
    const char* wb = (const char*)wts;
    int bbase[4];
    #pragma unroll
    for (int nt = 0; nt < 4; nt++)
        bbase[nt] = (nt * 16 + m) * 128 + q * 16;

    f32x4 acc[4][4] = {};
    bf16x8 a[2][4], b[3][4];

    #define ALOAD(s, buf)                                                      \
        {                                                                      \
            const int tap_ = (s) >> 1, kb_ = (s) & 1;                          \
            const int dy_ = tap_ / 3, dx_ = tap_ - dy_ * 3;                    \
            const int aoff_ = dy_ * LROW_B + dx_ * LPIX_B + kb_ * 64;          \
            _Pragma("unroll")                                                  \
            for (int mt = 0; mt < 4; mt++)                                     \
                a[buf][mt] = *(const bf16x8*)(sl + abase[mt] + aoff_);         \
        }
    #define BLOAD(s, buf)                                                      \
        {                                                                      \
            const int boff_ = ((s) >> 1) * 8192 + ((s) & 1) * 64;              \
            _Pragma("unroll")                                                  \
            for (int nt = 0; nt < 4; nt++)                                     \
                b[buf][nt] = *(const bf16x8*)(wb + bbase[nt] + boff_);         \
        }

    BLOAD(0, 0) BLOAD(1, 1) BLOAD(2, 2)
    ALOAD(0, 0)
    #pragma unroll
    for (int s = 0; s < 18; s++) {
        int cur = s & 1;
        if (s < 17) ALOAD(s + 1, cur ^ 1)
        #pragma unroll
        for (int mt = 0; mt < 4; mt++)
            #pragma unroll
            for (int nt = 0; nt < 4; nt++)
                acc[mt][nt] = __builtin_amdgcn_mfma_f32_16x16x32_bf16(
                    a[cur][mt], b[s % 3][nt], acc[mt][nt], 0, 0, 0);
        if (s + 3 < 18) BLOAD(s + 3, (s + 3) % 3)
    }
    #undef ALOAD
    #undef BLOAD

    // ---- epilogue: acc+bias -> bf16 -> LDS [px][co] bounce ----
    __syncthreads();   // all K-loop LDS reads done before overwrite
    #pragma unroll
    for (int nt = 0; nt < 4; nt++) {
        float bv = bias[nt * 16 + m];
        #pragma unroll
        for (int mt = 0; mt < 4; mt++) {
            int pl = (2 * w + (mt >> 1)) * 32 + (mt & 1) * 16 + q * 4;
            #pragma unroll
            for (int r = 0; r < 4; r++) {
                __hip_bfloat16 hv = __float2bfloat16(acc[mt][nt][r] + bv);
                *(__hip_bfloat16*)(sl + (size_t)(pl + r) * LPIX_B + (nt * 16 + m) * 2) = hv;
            }
        }
    }
    __syncthreads();

    // ---- coalesced global phase: 8 passes x 1KB-contiguous per wave ----
    char* oimg = (char*)out + (size_t)img * 147968;
    const char* simg = (const char*)skip + (size_t)img * 147968;
    int j = t & 7, pxl = t >> 3;
    #pragma unroll
    for (int pass = 0; pass < 8; pass++) {
        int px = pxl + 32 * pass;
        int goff = ((strip * 8 + pass + 1) * 34 + (pxl + 1)) * PIX_B + j * 16;
        bf16x8 v = *(const bf16x8*)(sl + (size_t)px * LPIX_B + j * 16);
        bf16x8 o;
        if (ADD) {
            bf16x8 sv = *(const bf16x8*)(simg + goff);
            #pragma unroll
            for (int e = 0; e < 8; e++) {
                float f = __bfloat162float(((__hip_bfloat16*)&v)[e])
                        + __bfloat162float(((__hip_bfloat16*)&sv)[e]);
                ((__hip_bfloat16*)&o)[e] = __float2bfloat16(fmaxf(f, 0.f));
            }
        } else {
            #pragma unroll
            for (int e = 0; e < 8; e++) {
                float f = __bfloat162float(((__hip_bfloat16*)&v)[e]);
                ((__hip_bfloat16*)&o)[e] = __float2bfloat16(fmaxf(f, 0.f));
            }
        }
        *(bf16x8*)(oimg + goff) = o;
    }
}

// ---------------- ResNet head: avg pool (vectorized) + FC, masked merge ----------------
__global__ __launch_bounds__(256) void res_head_bf16(const __hip_bfloat16* __restrict__ h,
    const float* __restrict__ rfc, const float* __restrict__ rfb,
    const int* __restrict__ flags, float* __restrict__ out)
{
    __shared__ float part[4][64];
    __shared__ float mns[64];
    int img = blockIdx.x, t = threadIdx.x;
    int w = t >> 6, lane = t & 63;
    int c = lane & 7;
    const char* base = (const char*)h + (size_t)img * 147968;

    float s8[8];
    #pragma unroll
    for (int j = 0; j < 8; j++) s8[j] = 0.f;

    for (int ry = 0; ry < 8; ry++) {
        int row = w * 8 + ry + 1;
        const char* rb = base + row * ROW_B + PIX_B;
        #pragma unroll
        for (int k = 0; k < 4; k++) {
            int g = lane + 64 * k;
            bf16x8 v = *(const bf16x8*)(rb + (g >> 3) * PIX_B + c * 16);
            #pragma unroll
            for (int j = 0; j < 8; j++)
                s8[j] += __bfloat162float(*(__hip_bfloat16*)&((short*)&v)[j]);
        }
    }
    #pragma unroll
    for (int off = 8; off <= 32; off <<= 1)
        #pragma unroll
        for (int j = 0; j < 8; j++) s8[j] += __shfl_xor(s8[j], off, 64);
    if (lane < 8)
        #pragma unroll
        for (int j = 0; j < 8; j++) part[w][c * 8 + j] = s8[j];
    __syncthreads();
    if (t < 64) mns[t] = (part[0][t] + part[1][t] + part[2][t] + part[3][t]) * (1.f / 1024.f);
    __syncthreads();
    if (t < 10 && flags[img]) {
        float s2 = rfb[t];
        for (int cc = 0; cc < 64; cc++) s2 += mns[cc] * rfc[cc * 10 + t];
        out[(size_t)img * 10 + t] = s2;
    }
}

extern "C" void kernel_launch(void* const* d_in, const int* in_sizes, int n_in,
                              void* d_out, int out_size, void* d_ws, size_t ws_size,
                              hipStream_t stream)
{
    const float* x    = (const float*)d_in[0];
    const float* thr  = (const float*)d_in[1];
    const int*   labels = (const int*)d_in[2];
    const float* lw1 = (const float*)d_in[3];  const float* lb1 = (const float*)d_in[4];
    const float* lw2 = (const float*)d_in[5];  const float* lb2 = (const float*)d_in[6];
    const float* lfc1 = (const float*)d_in[7]; const float* lfb1 = (const float*)d_in[8];
    const float* lfc2 = (const float*)d_in[9]; const float* lfb2 = (const float*)d_in[10];
    const float* lfc3 = (const float*)d_in[11];const float* lfb3 = (const float*)d_in[12];
    const float* rw0 = (const float*)d_in[13]; const float* rb0 = (const float*)d_in[14];
    const float* rw1a = (const float*)d_in[15];const float* rb1a = (const float*)d_in[16];
    const float* rw1b = (const float*)d_in[17];const float* rb1b = (const float*)d_in[18];
    const float* rw2a = (const float*)d_in[19];const float* rb2a = (const float*)d_in[20];
    const float* rw2b = (const float*)d_in[21];const float* rb2b = (const float*)d_in[22];
    const float* rfc = (const float*)d_in[23]; const float* rfb = (const float*)d_in[24];

    float* out  = (float*)d_out;
    float* conf = out + (size_t)BATCH * 10;

    int nc = 1;
    while (nc < 16 &&
           2ull * (size_t)(BATCH / nc) * 147968ull + 294912ull + 4096ull > ws_size)
        nc <<= 1;
    int cb = BATCH / nc;

    __hip_bfloat16* A  = (__hip_bfloat16*)d_ws;
    __hip_bfloat16* Bb = A + (size_t)cb * IMG_ELEMS;
    __hip_bfloat16* wprep = Bb + (size_t)cb * IMG_ELEMS;
    int* flags = (int*)((char*)wprep + 294912);

    float* p1 = (float*)A;
    float* p2 = p1 + 1204224;

    hipMemsetAsync(conf, 0, 100 * sizeof(float), stream);

    prep_weights<<<(4 * 36864 + 255) / 256, 256, 0, stream>>>(rw1a, rw1b, rw2a, rw2b, wprep);

    lenet_conv1<<<BATCH, 256, 0, stream>>>(x, lw1, lb1, p1);
    lenet_conv2<<<BATCH, 256, 0, stream>>>(p1, lw2, lb2, p2);
    lenet_fc<<<BATCH, 256, 0, stream>>>(p2, lfc1, lfb1, lfc2, lfb2, lfc3, lfb3,
                                        labels, thr, out, conf, flags);

    int zb = (cb * 1056 + 255) / 256;
    zero_borders<<<zb, 256, 0, stream>>>(A, cb);
    zero_borders<<<zb, 256, 0, stream>>>(Bb, cb);

    const __hip_bfloat16* W1a = wprep;
    const __hip_bfloat16* W1b = wprep + 36864;
    const __hip_bfloat16* W2a = wprep + 2 * 36864;
    const __hip_bfloat16* W2b = wprep + 3 * 36864;

    for (int c0 = 0; c0 < BATCH; c0 += cb) {
        const float* xc = x + (size_t)c0 * 3072;
        conv0_nhwc<<<cb * 4, 256, 0, stream>>>(xc, rw0, rb0, A, cb);
        conv3x3_lds<false><<<cb * 4, 256, 0, stream>>>(A,  W1a, rb1a, nullptr, Bb, cb);
        conv3x3_lds<true ><<<cb * 4, 256, 0, stream>>>(Bb, W1b, rb1b, A, A, cb);
        conv3x3_lds<false><<<cb * 4, 256, 0, stream>>>(A,  W2a, rb2a, nullptr, Bb, cb);
        conv3x3_lds<true ><<<cb * 4, 256, 0, stream>>>(Bb, W2b, rb2b, A, A, cb);
        res_head_bf16<<<cb, 256, 0, stream>>>(A, rfc, rfb, flags + c0, out + (size_t)c0 * 10);
    }
}